// Round 1
// baseline (255.265 us; speedup 1.0000x reference)
//
#include <hip/hip_runtime.h>
#include <math.h>

#define NCLS 5
#define NBINS 25
#define NBLOCKS 512
#define NTHREADS 256

// Kernel 1: stream preds/true, build per-block 25-bin confusion counts.
// Each thread handles 4 rows per grid-stride iteration:
//   5x float4 loads (80B contiguous, 16B-aligned since 4 rows = 20 floats)
//   1x int4 load for labels.
// LDS histogram -> atomic-free per-block partial write to d_ws.
__global__ void __launch_bounds__(NTHREADS)
kappa_count(const float* __restrict__ preds,
            const int* __restrict__ truev,
            int N,
            unsigned int* __restrict__ partials) {
    __shared__ unsigned int s_conf[NBINS];
    const int tid = threadIdx.x;
    if (tid < NBINS) s_conf[tid] = 0u;
    __syncthreads();

    const int nquad = N >> 2;
    const int gstride = gridDim.x * blockDim.x;
    for (int q = blockIdx.x * blockDim.x + tid; q < nquad; q += gstride) {
        const float4* p4 = (const float4*)(preds + (size_t)q * 20u);
        float4 a = p4[0];
        float4 b = p4[1];
        float4 c = p4[2];
        float4 d = p4[3];
        float4 e = p4[4];
        int4 t4 = *(const int4*)(truev + (size_t)q * 4u);

        float rows[4][NCLS] = {
            {a.x, a.y, a.z, a.w, b.x},
            {b.y, b.z, b.w, c.x, c.y},
            {c.z, c.w, d.x, d.y, d.z},
            {d.w, e.x, e.y, e.z, e.w}
        };
        int ts[4] = {t4.x, t4.y, t4.z, t4.w};

        #pragma unroll
        for (int r = 0; r < 4; r++) {
            float m = rows[r][0];
            #pragma unroll
            for (int j = 1; j < NCLS; j++) m = fmaxf(m, rows[r][j]);
            float s = 0.f, dot = 0.f;
            #pragma unroll
            for (int j = 0; j < NCLS; j++) {
                float ex = __expf(rows[r][j] - m);
                s += ex;
                dot += ex * (float)j;
            }
            int pi = (int)rintf(dot / s);      // round-half-even == jnp.round
            pi = min(max(pi, 0), NCLS - 1);
            atomicAdd(&s_conf[ts[r] * NCLS + pi], 1u);
        }
    }

    // Tail rows if N % 4 != 0 (N=8M is divisible; kept for safety).
    if (blockIdx.x == 0 && tid < (N & 3)) {
        int i = (N & ~3) + tid;
        float v[NCLS];
        #pragma unroll
        for (int j = 0; j < NCLS; j++) v[j] = preds[(size_t)i * NCLS + j];
        float m = v[0];
        #pragma unroll
        for (int j = 1; j < NCLS; j++) m = fmaxf(m, v[j]);
        float s = 0.f, dot = 0.f;
        #pragma unroll
        for (int j = 0; j < NCLS; j++) {
            float ex = __expf(v[j] - m);
            s += ex;
            dot += ex * (float)j;
        }
        int pi = (int)rintf(dot / s);
        pi = min(max(pi, 0), NCLS - 1);
        atomicAdd(&s_conf[truev[i] * NCLS + pi], 1u);
    }

    __syncthreads();
    if (tid < NBINS) partials[blockIdx.x * NBINS + tid] = s_conf[tid];
}

// Kernel 2: reduce per-block partials, do the O(25) kappa math in double.
// kappa = tot * sum(w*conf) / sum(w_ij * th_i * ph_j)
__global__ void kappa_final(const unsigned int* __restrict__ partials,
                            int nblocks,
                            float* __restrict__ out) {
    __shared__ unsigned int s_conf[NBINS];
    const int tid = threadIdx.x;
    if (tid < NBINS) s_conf[tid] = 0u;
    __syncthreads();

    const int total = nblocks * NBINS;
    for (int i = tid; i < total; i += blockDim.x) {
        unsigned int v = partials[i];
        if (v) atomicAdd(&s_conf[i % NBINS], v);
    }
    __syncthreads();

    if (tid == 0) {
        double conf[NBINS];
        double tot = 0.0;
        for (int i = 0; i < NBINS; i++) { conf[i] = (double)s_conf[i]; tot += conf[i]; }
        double th[NCLS] = {0, 0, 0, 0, 0};
        double ph[NCLS] = {0, 0, 0, 0, 0};
        for (int i = 0; i < NCLS; i++)
            for (int j = 0; j < NCLS; j++) {
                th[i] += conf[i * NCLS + j];
                ph[j] += conf[i * NCLS + j];
            }
        double num = 0.0, den = 0.0;
        for (int i = 0; i < NCLS; i++)
            for (int j = 0; j < NCLS; j++) {
                double w = (double)((i - j) * (i - j)) / 16.0;  // (C-1)^2 = 16
                num += w * conf[i * NCLS + j];
                den += w * th[i] * ph[j];
            }
        // num/tot divided by den/tot^2  ==  num*tot/den
        out[0] = (float)(num * tot / den);
    }
}

extern "C" void kernel_launch(void* const* d_in, const int* in_sizes, int n_in,
                              void* d_out, int out_size, void* d_ws, size_t ws_size,
                              hipStream_t stream) {
    const float* preds = (const float*)d_in[0];
    const int* truev = (const int*)d_in[1];
    const int N = in_sizes[1];  // number of samples (true is [N])

    int nblocks = NBLOCKS;
    size_t need = (size_t)nblocks * NBINS * sizeof(unsigned int);
    if (need > ws_size) nblocks = (int)(ws_size / (NBINS * sizeof(unsigned int)));
    unsigned int* partials = (unsigned int*)d_ws;

    kappa_count<<<nblocks, NTHREADS, 0, stream>>>(preds, truev, N, partials);
    kappa_final<<<1, 256, 0, stream>>>(partials, nblocks, (float*)d_out);
}